// Round 1
// baseline (89.013 us; speedup 1.0000x reference)
//
#include <hip/hip_runtime.h>
#include <hip/hip_bf16.h>

// Inverse pose: in[b] = [R | t] (3x4 row-major), out[b] = [R^T | -R^T t].
// Pure memory-bound: 48B in + 48B out per pose, ~15 FLOPs.
// One thread per pose; 3x float4 load, register transpose, 3x float4 store.

__global__ __launch_bounds__(256) void inverse_pose_kernel(
    const float4* __restrict__ in, float4* __restrict__ out, int n_poses) {
    const int stride = gridDim.x * blockDim.x;
    for (int i = blockIdx.x * blockDim.x + threadIdx.x; i < n_poses; i += stride) {
        // Each pose = 3 float4 rows: (r00,r01,r02,t0), (r10,r11,r12,t1), (r20,r21,r22,t2)
        const float4 a0 = in[i * 3 + 0];
        const float4 a1 = in[i * 3 + 1];
        const float4 a2 = in[i * 3 + 2];

        // u = -R^T t : u_j = -(r0j*t0 + r1j*t1 + r2j*t2)
        float4 o0, o1, o2;
        o0.x = a0.x; o0.y = a1.x; o0.z = a2.x;
        o1.x = a0.y; o1.y = a1.y; o1.z = a2.y;
        o2.x = a0.z; o2.y = a1.z; o2.z = a2.z;
        o0.w = -(a0.x * a0.w + a1.x * a1.w + a2.x * a2.w);
        o1.w = -(a0.y * a0.w + a1.y * a1.w + a2.y * a2.w);
        o2.w = -(a0.z * a0.w + a1.z * a1.w + a2.z * a2.w);

        out[i * 3 + 0] = o0;
        out[i * 3 + 1] = o1;
        out[i * 3 + 2] = o2;
    }
}

extern "C" void kernel_launch(void* const* d_in, const int* in_sizes, int n_in,
                              void* d_out, int out_size, void* d_ws, size_t ws_size,
                              hipStream_t stream) {
    const float4* in = (const float4*)d_in[0];
    float4* out = (float4*)d_out;
    const int n_poses = in_sizes[0] / 12;  // 4,000,000

    const int block = 256;
    int grid = (n_poses + block - 1) / block;
    if (grid > 2048) grid = 2048;  // grid-stride; ~8 blocks/CU across 256 CUs
    inverse_pose_kernel<<<grid, block, 0, stream>>>(in, out, n_poses);
}

// Round 2
// 73.824 us; speedup vs baseline: 1.2057x; 1.2057x over previous
//
#include <hip/hip_runtime.h>
#include <hip/hip_bf16.h>

// Inverse pose: in[b] = [R | t] (3x4 row-major), out[b] = [R^T | -R^T t].
// LDS-staged version: global accesses are perfectly dense per instruction
// (lane i <-> float4 i), the 48B-stride pose gather happens in LDS.
// Per block: 256 poses = 768 float4 = 12KB in + 12KB out LDS.

#define PB 256  // poses per block (== blockDim.x)

__global__ __launch_bounds__(256) void inverse_pose_lds(
    const float4* __restrict__ in, float4* __restrict__ out) {
    __shared__ float4 s_in[PB * 3];
    __shared__ float4 s_out[PB * 3];

    const int t = threadIdx.x;
    const int base = blockIdx.x * (PB * 3);  // < 12M, fits int

    // Stage in: dense coalesced loads, dense LDS writes (conflict-free).
#pragma unroll
    for (int k = 0; k < 3; ++k)
        s_in[t + k * PB] = in[base + t + k * PB];
    __syncthreads();

    // Gather one pose per thread from LDS (bank stride 12 -> all 32 banks
    // covered every 8 lanes; ~2-way, free).
    const float4 a0 = s_in[3 * t + 0];
    const float4 a1 = s_in[3 * t + 1];
    const float4 a2 = s_in[3 * t + 2];

    float4 o0, o1, o2;
    o0.x = a0.x; o0.y = a1.x; o0.z = a2.x;
    o1.x = a0.y; o1.y = a1.y; o1.z = a2.y;
    o2.x = a0.z; o2.y = a1.z; o2.z = a2.z;
    o0.w = -(a0.x * a0.w + a1.x * a1.w + a2.x * a2.w);
    o1.w = -(a0.y * a0.w + a1.y * a1.w + a2.y * a2.w);
    o2.w = -(a0.z * a0.w + a1.z * a1.w + a2.z * a2.w);

    s_out[3 * t + 0] = o0;
    s_out[3 * t + 1] = o1;
    s_out[3 * t + 2] = o2;
    __syncthreads();

    // Stage out: dense LDS reads, dense coalesced global stores.
#pragma unroll
    for (int k = 0; k < 3; ++k)
        out[base + t + k * PB] = s_out[t + k * PB];
}

// Tail fallback (not used at B=4M since 4,000,000 % 256 == 0, but kept for
// generality): one thread per pose, direct.
__global__ __launch_bounds__(256) void inverse_pose_tail(
    const float4* __restrict__ in, float4* __restrict__ out,
    int first_pose, int n_poses) {
    const int i = first_pose + blockIdx.x * blockDim.x + threadIdx.x;
    if (i >= n_poses) return;
    const float4 a0 = in[i * 3 + 0];
    const float4 a1 = in[i * 3 + 1];
    const float4 a2 = in[i * 3 + 2];
    float4 o0, o1, o2;
    o0.x = a0.x; o0.y = a1.x; o0.z = a2.x;
    o1.x = a0.y; o1.y = a1.y; o1.z = a2.y;
    o2.x = a0.z; o2.y = a1.z; o2.z = a2.z;
    o0.w = -(a0.x * a0.w + a1.x * a1.w + a2.x * a2.w);
    o1.w = -(a0.y * a0.w + a1.y * a1.w + a2.y * a2.w);
    o2.w = -(a0.z * a0.w + a1.z * a1.w + a2.z * a2.w);
    out[i * 3 + 0] = o0;
    out[i * 3 + 1] = o1;
    out[i * 3 + 2] = o2;
}

extern "C" void kernel_launch(void* const* d_in, const int* in_sizes, int n_in,
                              void* d_out, int out_size, void* d_ws, size_t ws_size,
                              hipStream_t stream) {
    const float4* in = (const float4*)d_in[0];
    float4* out = (float4*)d_out;
    const int n_poses = in_sizes[0] / 12;  // 4,000,000

    const int full_blocks = n_poses / PB;  // 15625 exactly at B=4M
    const int rem = n_poses % PB;

    if (full_blocks > 0)
        inverse_pose_lds<<<full_blocks, PB, 0, stream>>>(in, out);
    if (rem > 0) {
        const int first = full_blocks * PB;
        inverse_pose_tail<<<(rem + 255) / 256, 256, 0, stream>>>(in, out, first, n_poses);
    }
}

// Round 4
// 60.313 us; speedup vs baseline: 1.4759x; 1.2240x over previous
//
#include <hip/hip_runtime.h>
#include <hip/hip_bf16.h>

// Inverse pose: in[b] = [R | t] (3x4 row-major), out[b] = [R^T | -R^T t].
// v3b: single LDS buffer (12KB -> 8 blocks/CU) + non-temporal stores
// (via clang native vector type, which __builtin_nontemporal_store accepts)
// so the 192MB output stream doesn't evict the 192MB input from the 256MB L3.

#define PB 256  // poses per block (== blockDim.x)

typedef float f32x4 __attribute__((ext_vector_type(4)));

__global__ __launch_bounds__(256) void inverse_pose_lds(
    const f32x4* __restrict__ in, f32x4* __restrict__ out) {
    __shared__ f32x4 s[PB * 3];  // 12 KB, reused for in then out

    const int t = threadIdx.x;
    const int base = blockIdx.x * (PB * 3);  // < 12M, fits int

    // Dense coalesced loads into registers, then dense LDS writes.
    const f32x4 r0 = in[base + t];
    const f32x4 r1 = in[base + t + PB];
    const f32x4 r2 = in[base + t + 2 * PB];
    s[t] = r0;
    s[t + PB] = r1;
    s[t + 2 * PB] = r2;
    __syncthreads();

    // Gather one pose per thread (stride-12 float4: each 8-lane group covers
    // all 32 banks exactly once -> conflict-free).
    const f32x4 a0 = s[3 * t + 0];
    const f32x4 a1 = s[3 * t + 1];
    const f32x4 a2 = s[3 * t + 2];
    __syncthreads();  // all reads done before in-place overwrite

    f32x4 o0, o1, o2;
    o0.x = a0.x; o0.y = a1.x; o0.z = a2.x;
    o1.x = a0.y; o1.y = a1.y; o1.z = a2.y;
    o2.x = a0.z; o2.y = a1.z; o2.z = a2.z;
    o0.w = -(a0.x * a0.w + a1.x * a1.w + a2.x * a2.w);
    o1.w = -(a0.y * a0.w + a1.y * a1.w + a2.y * a2.w);
    o2.w = -(a0.z * a0.w + a1.z * a1.w + a2.z * a2.w);

    s[3 * t + 0] = o0;
    s[3 * t + 1] = o1;
    s[3 * t + 2] = o2;
    __syncthreads();

    // Dense LDS reads, dense non-temporal global stores (don't pollute L3).
    __builtin_nontemporal_store(s[t],          &out[base + t]);
    __builtin_nontemporal_store(s[t + PB],     &out[base + t + PB]);
    __builtin_nontemporal_store(s[t + 2 * PB], &out[base + t + 2 * PB]);
}

// Tail fallback (unused at B=4M; 4,000,000 % 256 == 0).
__global__ __launch_bounds__(256) void inverse_pose_tail(
    const f32x4* __restrict__ in, f32x4* __restrict__ out,
    int first_pose, int n_poses) {
    const int i = first_pose + blockIdx.x * blockDim.x + threadIdx.x;
    if (i >= n_poses) return;
    const f32x4 a0 = in[i * 3 + 0];
    const f32x4 a1 = in[i * 3 + 1];
    const f32x4 a2 = in[i * 3 + 2];
    f32x4 o0, o1, o2;
    o0.x = a0.x; o0.y = a1.x; o0.z = a2.x;
    o1.x = a0.y; o1.y = a1.y; o1.z = a2.y;
    o2.x = a0.z; o2.y = a1.z; o2.z = a2.z;
    o0.w = -(a0.x * a0.w + a1.x * a1.w + a2.x * a2.w);
    o1.w = -(a0.y * a0.w + a1.y * a1.w + a2.y * a2.w);
    o2.w = -(a0.z * a0.w + a1.z * a1.w + a2.z * a2.w);
    out[i * 3 + 0] = o0;
    out[i * 3 + 1] = o1;
    out[i * 3 + 2] = o2;
}

extern "C" void kernel_launch(void* const* d_in, const int* in_sizes, int n_in,
                              void* d_out, int out_size, void* d_ws, size_t ws_size,
                              hipStream_t stream) {
    const f32x4* in = (const f32x4*)d_in[0];
    f32x4* out = (f32x4*)d_out;
    const int n_poses = in_sizes[0] / 12;  // 4,000,000

    const int full_blocks = n_poses / PB;  // 15625 exactly at B=4M
    const int rem = n_poses % PB;

    if (full_blocks > 0)
        inverse_pose_lds<<<full_blocks, PB, 0, stream>>>(in, out);
    if (rem > 0) {
        const int first = full_blocks * PB;
        inverse_pose_tail<<<(rem + 255) / 256, 256, 0, stream>>>(in, out, first, n_poses);
    }
}